// Round 2
// baseline (684.455 us; speedup 1.0000x reference)
//
#include <hip/hip_runtime.h>

// SSIM over (32,3,512,512) fp32 pairs, 11x11 gaussian sigma=1.5, VALID conv,
// scalar mean output. Fused separable conv: vertical pass in registers
// (thread owns a column pair), 5-channel v-stats staged in LDS (XOR-swizzled),
// horizontal 11-tap conv register-blocked 8 cols/thread, SSIM + mean fused.
//
// R1 (resubmit after broker timeout): occupancy push. QR 4->2 shrinks LDS
// 44KB->21.8KB => 6 blocks/CU (24 waves/CU, was 12). RPB=32 makes grid
// 16x96=1536 = exactly 6/CU, whole grid co-resident. Row clamp removed
// (provably in-bounds). Epilogue div -> rcp.

namespace {
constexpr int IMG_H = 512;
constexpr int IMG_W = 512;
constexpr int NIMG  = 96;            // B*C = 32*3
constexpr int OUT_H = 502;
constexpr int OUT_W = 502;
constexpr int RPB   = 32;            // output rows per block
constexpr int QR    = 2;             // output rows per inner iteration
constexpr int BUFW  = 544;           // 136 col4 slots * 4 floats (512 data + halo/pad)
constexpr double TOTAL = 24192384.0; // 96*502*502

// exp(-k^2/4.5) for k=5..1, normalized at compile time
constexpr double U0 = 0.0038659201;
constexpr double U1 = 0.0285655007;
constexpr double U2 = 0.1353352832366127;
constexpr double U3 = 0.4111122898;
constexpr double U4 = 0.8007374026;
constexpr double S  = 1.0 + 2.0 * (U0 + U1 + U2 + U3 + U4);
}

__device__ __forceinline__ float2 f2fma(float w, float2 a, float2 c) {
    return make_float2(fmaf(w, a.x, c.x), fmaf(w, a.y, c.y));
}

__global__ __launch_bounds__(256, 6) void ssim_main(const float* __restrict__ img1,
                                                    const float* __restrict__ img2,
                                                    double* __restrict__ acc)
{
    __shared__ __align__(16) float vrow[QR][5][BUFW];
    __shared__ float red[4];

    const float g[11] = {
        (float)(U0/S), (float)(U1/S), (float)(U2/S), (float)(U3/S), (float)(U4/S),
        (float)(1.0/S),
        (float)(U4/S), (float)(U3/S), (float)(U2/S), (float)(U1/S), (float)(U0/S)
    };
    constexpr float C1 = 1e-4f;   // 0.01^2
    constexpr float C2 = 9e-4f;   // 0.03^2

    const int t   = threadIdx.x;
    const int z   = blockIdx.y;
    const int oy0 = blockIdx.x * RPB;
    const int row_end = min(oy0 + RPB, OUT_H);

    const float2* p1 = (const float2*)(img1 + (size_t)z * (IMG_H * IMG_W)) + t;
    const float2* p2 = (const float2*)(img2 + (size_t)z * (IMG_H * IMG_W)) + t;

    // phase-V: thread owns input cols 2t, 2t+1. Swizzled write offset.
    const int c4w  = t >> 1;
    const int woff = ((c4w ^ ((c4w >> 3) & 7)) << 2) + ((t & 1) << 1);

    // phase-H: thread = (row-in-group hq, 8-col group at cb). Swizzled read offsets.
    const int hq = t >> 6;
    const int hl = t & 63;
    const int cb = hl << 3;
    int roff[5];
    #pragma unroll
    for (int k = 0; k < 5; ++k) {
        int c4 = (cb >> 2) + k;
        roff[k] = (c4 ^ ((c4 >> 3) & 7)) << 2;
    }

    float local = 0.f;

    for (int r0 = oy0; r0 < row_end; r0 += QR) {
        // ---------------- phase V: vertical 11-tap conv, registers ----------------
        // max input row touched = 500 + 11 = 511 < IMG_H: no clamp needed.
        float2 xr[QR + 10], yr[QR + 10];
        #pragma unroll
        for (int j = 0; j < QR + 10; ++j) {
            const int row = r0 + j;
            xr[j] = p1[row * (IMG_W / 2)];
            yr[j] = p2[row * (IMG_W / 2)];
        }
        float2 vm1[QR], vm2[QR], v11[QR], v22[QR], v12[QR];
        #pragma unroll
        for (int q = 0; q < QR; ++q) {
            vm1[q] = make_float2(0.f, 0.f);
            vm2[q] = make_float2(0.f, 0.f);
            v11[q] = make_float2(0.f, 0.f);
            v22[q] = make_float2(0.f, 0.f);
            v12[q] = make_float2(0.f, 0.f);
        }
        #pragma unroll
        for (int j = 0; j < QR + 10; ++j) {
            float2 x = xr[j], y = yr[j];
            float2 xx = make_float2(x.x * x.x, x.y * x.y);
            float2 yy = make_float2(y.x * y.x, y.y * y.y);
            float2 xy = make_float2(x.x * y.x, x.y * y.y);
            #pragma unroll
            for (int q = 0; q < QR; ++q) {
                int k = j - q;
                if (k >= 0 && k < 11) {
                    float w = g[k];
                    vm1[q] = f2fma(w, x,  vm1[q]);
                    vm2[q] = f2fma(w, y,  vm2[q]);
                    v11[q] = f2fma(w, xx, v11[q]);
                    v22[q] = f2fma(w, yy, v22[q]);
                    v12[q] = f2fma(w, xy, v12[q]);
                }
            }
        }
        __syncthreads();   // previous iteration's phase-H reads complete
        #pragma unroll
        for (int q = 0; q < QR; ++q) {
            *(float2*)&vrow[q][0][woff] = vm1[q];
            *(float2*)&vrow[q][1][woff] = vm2[q];
            *(float2*)&vrow[q][2][woff] = v11[q];
            *(float2*)&vrow[q][3][woff] = v22[q];
            *(float2*)&vrow[q][4][woff] = v12[q];
        }
        __syncthreads();

        // ---------------- phase H: horizontal 11-tap conv + SSIM ----------------
        const int rr = r0 + hq;
        if (hq < QR && rr < row_end && cb < OUT_W) {
            float aa[5][8];
            #pragma unroll
            for (int ch = 0; ch < 5; ++ch) {
                const float* bc = &vrow[hq][ch][0];
                float f[20];
                #pragma unroll
                for (int k = 0; k < 5; ++k) {
                    float4 v = *(const float4*)(bc + roff[k]);
                    f[4*k+0] = v.x; f[4*k+1] = v.y; f[4*k+2] = v.z; f[4*k+3] = v.w;
                }
                #pragma unroll
                for (int j = 0; j < 8; ++j) {
                    float s = 0.f;
                    #pragma unroll
                    for (int k = 0; k < 11; ++k) s = fmaf(g[k], f[j + k], s);
                    aa[ch][j] = s;
                }
            }
            #pragma unroll
            for (int j = 0; j < 8; ++j) {
                if (cb + j < OUT_W) {
                    float mu1 = aa[0][j], mu2 = aa[1][j];
                    float e11 = aa[2][j], e22 = aa[3][j], e12 = aa[4][j];
                    float mu11 = mu1 * mu1;
                    float mu22 = mu2 * mu2;
                    float mu12 = mu1 * mu2;
                    float s1  = e11 - mu11;
                    float s2  = e22 - mu22;
                    float s12 = e12 - mu12;
                    float num = fmaf(2.f, mu12, C1) * fmaf(2.f, s12, C2);
                    float den = (mu11 + mu22 + C1) * (s1 + s2 + C2);
                    local = fmaf(num, __builtin_amdgcn_rcpf(den), local);
                }
            }
        }
    }

    // ---------------- reduction: wave shuffle -> LDS -> double atomic ----------------
    #pragma unroll
    for (int off = 32; off > 0; off >>= 1) local += __shfl_down(local, off, 64);
    if ((t & 63) == 0) red[t >> 6] = local;
    __syncthreads();
    if (t == 0) {
        double s = (double)red[0] + (double)red[1] + (double)red[2] + (double)red[3];
        atomicAdd(acc, s);
    }
}

__global__ void ssim_fin(const double* __restrict__ acc, float* __restrict__ out)
{
    out[0] = (float)(acc[0] / TOTAL);
}

extern "C" void kernel_launch(void* const* d_in, const int* in_sizes, int n_in,
                              void* d_out, int out_size, void* d_ws, size_t ws_size,
                              hipStream_t stream)
{
    (void)in_sizes; (void)n_in; (void)out_size; (void)ws_size;
    const float* img1 = (const float*)d_in[0];
    const float* img2 = (const float*)d_in[1];
    double* acc = (double*)d_ws;

    hipMemsetAsync(d_ws, 0, sizeof(double), stream);
    dim3 grid((OUT_H + RPB - 1) / RPB, NIMG);
    hipLaunchKernelGGL(ssim_main, grid, dim3(256), 0, stream, img1, img2, acc);
    hipLaunchKernelGGL(ssim_fin, dim3(1), dim3(1), 0, stream, acc, (float*)d_out);
}

// Round 3
// 293.271 us; speedup vs baseline: 2.3339x; 2.3339x over previous
//
#include <hip/hip_runtime.h>

// SSIM over (32,3,512,512) fp32 pairs, 11x11 gaussian sigma=1.5, VALID conv,
// scalar mean output. Fused separable conv, 5 v-stats staged in LDS
// (XOR-swizzled), horizontal 11-tap conv + SSIM + mean fused in epilogue.
//
// R2: fit the structure under the proven launch_bounds(256,3) => 80-VGPR cap
// (hipcc cap = floor(256/N); N=6 gave 40 regs + 708MB scratch spill in R1).
// Occupancy comes from ACTUAL regs: 80 VGPR -> 6 waves/SIMD; LDS 21.8KB -> 7
// blocks/CU; net 6 blocks/CU (was 3). Reg cuts: (a) streaming phase-V (no
// xr/yr[12] row arrays, -48 regs), (b) phase-H rebalanced to 2 rows x 128
// threads x 4 cols (all 256 threads active, was half idle; aa+f 60->36 regs).

namespace {
constexpr int IMG_H = 512;
constexpr int IMG_W = 512;
constexpr int NIMG  = 96;            // B*C = 32*3
constexpr int OUT_H = 502;
constexpr int OUT_W = 502;
constexpr int RPB   = 32;            // output rows per block
constexpr int QR    = 2;             // output rows per inner iteration
constexpr int BUFW  = 544;           // 136 col4 slots * 4 floats (512 data + halo/pad)
constexpr double TOTAL = 24192384.0; // 96*502*502

// exp(-k^2/4.5) for k=5..1, normalized at compile time
constexpr double U0 = 0.0038659201;
constexpr double U1 = 0.0285655007;
constexpr double U2 = 0.1353352832366127;
constexpr double U3 = 0.4111122898;
constexpr double U4 = 0.8007374026;
constexpr double S  = 1.0 + 2.0 * (U0 + U1 + U2 + U3 + U4);
}

__device__ __forceinline__ float2 f2fma(float w, float2 a, float2 c) {
    return make_float2(fmaf(w, a.x, c.x), fmaf(w, a.y, c.y));
}

__global__ __launch_bounds__(256, 3) void ssim_main(const float* __restrict__ img1,
                                                    const float* __restrict__ img2,
                                                    double* __restrict__ acc)
{
    __shared__ __align__(16) float vrow[QR][5][BUFW];   // 21760 B
    __shared__ float red[4];

    const float g[11] = {
        (float)(U0/S), (float)(U1/S), (float)(U2/S), (float)(U3/S), (float)(U4/S),
        (float)(1.0/S),
        (float)(U4/S), (float)(U3/S), (float)(U2/S), (float)(U1/S), (float)(U0/S)
    };
    constexpr float C1 = 1e-4f;   // 0.01^2
    constexpr float C2 = 9e-4f;   // 0.03^2

    const int t   = threadIdx.x;
    const int z   = blockIdx.y;
    const int oy0 = blockIdx.x * RPB;
    const int row_end = min(oy0 + RPB, OUT_H);

    const float2* p1 = (const float2*)(img1 + (size_t)z * (IMG_H * IMG_W)) + t;
    const float2* p2 = (const float2*)(img2 + (size_t)z * (IMG_H * IMG_W)) + t;

    // phase-V: thread owns input cols 2t, 2t+1. Swizzled write offset.
    const int c4w  = t >> 1;
    const int woff = ((c4w ^ ((c4w >> 3) & 7)) << 2) + ((t & 1) << 1);

    // phase-H: thread = (row hq in 0..1, 4-col group at cb). Swizzled read offsets.
    const int hq = t >> 7;            // 0..1  (all 256 threads active)
    const int cb = (t & 127) << 2;    // 0..508
    int roff[4];
    #pragma unroll
    for (int k = 0; k < 4; ++k) {
        int c4 = (cb >> 2) + k;       // <= 130 < 136 slots, float4 read stays in BUFW
        roff[k] = (c4 ^ ((c4 >> 3) & 7)) << 2;
    }

    float local = 0.f;

    for (int r0 = oy0; r0 < row_end; r0 += QR) {
        // ------------- phase V: vertical 11-tap conv, streaming registers -------------
        // max input row touched = 500 + 11 = 511 < IMG_H: no clamp needed.
        float2 vm1[QR], vm2[QR], v11[QR], v22[QR], v12[QR];
        #pragma unroll
        for (int q = 0; q < QR; ++q) {
            vm1[q] = make_float2(0.f, 0.f);
            vm2[q] = make_float2(0.f, 0.f);
            v11[q] = make_float2(0.f, 0.f);
            v22[q] = make_float2(0.f, 0.f);
            v12[q] = make_float2(0.f, 0.f);
        }
        #pragma unroll
        for (int j = 0; j < QR + 10; ++j) {
            const float2 x = p1[(r0 + j) * (IMG_W / 2)];
            const float2 y = p2[(r0 + j) * (IMG_W / 2)];
            const float2 xx = make_float2(x.x * x.x, x.y * x.y);
            const float2 yy = make_float2(y.x * y.x, y.y * y.y);
            const float2 xy = make_float2(x.x * y.x, x.y * y.y);
            #pragma unroll
            for (int q = 0; q < QR; ++q) {
                const int k = j - q;
                if (k >= 0 && k < 11) {
                    const float w = g[k];
                    vm1[q] = f2fma(w, x,  vm1[q]);
                    vm2[q] = f2fma(w, y,  vm2[q]);
                    v11[q] = f2fma(w, xx, v11[q]);
                    v22[q] = f2fma(w, yy, v22[q]);
                    v12[q] = f2fma(w, xy, v12[q]);
                }
            }
        }
        __syncthreads();   // previous iteration's phase-H reads complete
        #pragma unroll
        for (int q = 0; q < QR; ++q) {
            *(float2*)&vrow[q][0][woff] = vm1[q];
            *(float2*)&vrow[q][1][woff] = vm2[q];
            *(float2*)&vrow[q][2][woff] = v11[q];
            *(float2*)&vrow[q][3][woff] = v22[q];
            *(float2*)&vrow[q][4][woff] = v12[q];
        }
        __syncthreads();

        // ------------- phase H: horizontal 11-tap conv + SSIM, 4 cols/thread -------------
        const int rr = r0 + hq;
        if (rr < row_end) {
            float aa[5][4];
            #pragma unroll
            for (int ch = 0; ch < 5; ++ch) {
                const float* bc = &vrow[hq][ch][0];
                float f[16];
                #pragma unroll
                for (int k = 0; k < 4; ++k) {
                    float4 v = *(const float4*)(bc + roff[k]);
                    f[4*k+0] = v.x; f[4*k+1] = v.y; f[4*k+2] = v.z; f[4*k+3] = v.w;
                }
                #pragma unroll
                for (int j = 0; j < 4; ++j) {
                    float s = 0.f;
                    #pragma unroll
                    for (int k = 0; k < 11; ++k) s = fmaf(g[k], f[j + k], s);
                    aa[ch][j] = s;
                }
            }
            #pragma unroll
            for (int j = 0; j < 4; ++j) {
                if (cb + j < OUT_W) {
                    float mu1 = aa[0][j], mu2 = aa[1][j];
                    float e11 = aa[2][j], e22 = aa[3][j], e12 = aa[4][j];
                    float mu11 = mu1 * mu1;
                    float mu22 = mu2 * mu2;
                    float mu12 = mu1 * mu2;
                    float s1  = e11 - mu11;
                    float s2  = e22 - mu22;
                    float s12 = e12 - mu12;
                    float num = fmaf(2.f, mu12, C1) * fmaf(2.f, s12, C2);
                    float den = (mu11 + mu22 + C1) * (s1 + s2 + C2);
                    local = fmaf(num, __builtin_amdgcn_rcpf(den), local);
                }
            }
        }
    }

    // ---------------- reduction: wave shuffle -> LDS -> double atomic ----------------
    #pragma unroll
    for (int off = 32; off > 0; off >>= 1) local += __shfl_down(local, off, 64);
    if ((t & 63) == 0) red[t >> 6] = local;
    __syncthreads();
    if (t == 0) {
        double s = (double)red[0] + (double)red[1] + (double)red[2] + (double)red[3];
        atomicAdd(acc, s);
    }
}

__global__ void ssim_fin(const double* __restrict__ acc, float* __restrict__ out)
{
    out[0] = (float)(acc[0] / TOTAL);
}

extern "C" void kernel_launch(void* const* d_in, const int* in_sizes, int n_in,
                              void* d_out, int out_size, void* d_ws, size_t ws_size,
                              hipStream_t stream)
{
    (void)in_sizes; (void)n_in; (void)out_size; (void)ws_size;
    const float* img1 = (const float*)d_in[0];
    const float* img2 = (const float*)d_in[1];
    double* acc = (double*)d_ws;

    hipMemsetAsync(d_ws, 0, sizeof(double), stream);
    dim3 grid((OUT_H + RPB - 1) / RPB, NIMG);
    hipLaunchKernelGGL(ssim_main, grid, dim3(256), 0, stream, img1, img2, acc);
    hipLaunchKernelGGL(ssim_fin, dim3(1), dim3(1), 0, stream, acc, (float*)d_out);
}

// Round 4
// 288.597 us; speedup vs baseline: 2.3717x; 1.0162x over previous
//
#include <hip/hip_runtime.h>

// SSIM over (32,3,512,512) fp32 pairs, 11x11 gaussian sigma=1.5, VALID conv,
// scalar mean output. Fused separable conv, v-stats staged in LDS
// (XOR-swizzled), horizontal 11-tap conv + SSIM + mean fused in epilogue.
//
// R3: (a) 4 conv channels instead of 5 — SSIM only needs e11+e22, so convolve
// (x, y, x^2+y^2, x*y): -20% conv FMAs and LDS traffic. (b) double-buffered
// vrow with ONE barrier per iteration (was 2): H(i) and V(i+1) overlap in a
// barrier-free region. (c) RPB=64 restores R0's L2 locality (R2's RPB=32 at
// 6 blocks/CU thrashed L2: FETCH 194->382MB). LDS 34.8KB -> 4 blocks/CU cap.
// Keep launch_bounds(256,3): 85-reg cap, proven no-spill.

namespace {
constexpr int IMG_H = 512;
constexpr int IMG_W = 512;
constexpr int NIMG  = 96;            // B*C = 32*3
constexpr int OUT_H = 502;
constexpr int OUT_W = 502;
constexpr int RPB   = 64;            // output rows per block
constexpr int QR    = 2;             // output rows per inner iteration
constexpr int BUFW  = 544;           // 136 col4 slots * 4 floats (512 data + halo/pad)
constexpr double TOTAL = 24192384.0; // 96*502*502

// exp(-k^2/4.5) for k=5..1, normalized at compile time
constexpr double U0 = 0.0038659201;
constexpr double U1 = 0.0285655007;
constexpr double U2 = 0.1353352832366127;
constexpr double U3 = 0.4111122898;
constexpr double U4 = 0.8007374026;
constexpr double S  = 1.0 + 2.0 * (U0 + U1 + U2 + U3 + U4);
}

__device__ __forceinline__ float2 f2fma(float w, float2 a, float2 c) {
    return make_float2(fmaf(w, a.x, c.x), fmaf(w, a.y, c.y));
}

__global__ __launch_bounds__(256, 3) void ssim_main(const float* __restrict__ img1,
                                                    const float* __restrict__ img2,
                                                    double* __restrict__ acc)
{
    __shared__ __align__(16) float vrow[2][QR][4][BUFW];   // 34816 B, double-buffered
    __shared__ float red[4];

    const float g[11] = {
        (float)(U0/S), (float)(U1/S), (float)(U2/S), (float)(U3/S), (float)(U4/S),
        (float)(1.0/S),
        (float)(U4/S), (float)(U3/S), (float)(U2/S), (float)(U1/S), (float)(U0/S)
    };
    constexpr float C1 = 1e-4f;   // 0.01^2
    constexpr float C2 = 9e-4f;   // 0.03^2

    const int t   = threadIdx.x;
    const int z   = blockIdx.y;
    const int oy0 = blockIdx.x * RPB;
    const int row_end = min(oy0 + RPB, OUT_H);

    const float2* p1 = (const float2*)(img1 + (size_t)z * (IMG_H * IMG_W)) + t;
    const float2* p2 = (const float2*)(img2 + (size_t)z * (IMG_H * IMG_W)) + t;

    // phase-V: thread owns input cols 2t, 2t+1. Swizzled write offset.
    const int c4w  = t >> 1;
    const int woff = ((c4w ^ ((c4w >> 3) & 7)) << 2) + ((t & 1) << 1);

    // phase-H: thread = (row hq in 0..1, 4-col group at cb). Swizzled read offsets.
    const int hq = t >> 7;            // 0..1  (all 256 threads active)
    const int cb = (t & 127) << 2;    // 0..508
    int roff[4];
    #pragma unroll
    for (int k = 0; k < 4; ++k) {
        int c4 = (cb >> 2) + k;       // <= 130 < 136 slots, float4 read stays in BUFW
        roff[k] = (c4 ^ ((c4 >> 3) & 7)) << 2;
    }

    float local = 0.f;
    int p = 0;

    for (int r0 = oy0; r0 < row_end; r0 += QR, p ^= 1) {
        // ------------- phase V: vertical 11-tap conv, streaming, 4 channels -------------
        // max input row touched = 500 + 11 = 511 < IMG_H: no clamp needed.
        float2 am1[QR], am2[QR], app[QR], axy[QR];
        #pragma unroll
        for (int q = 0; q < QR; ++q) {
            am1[q] = make_float2(0.f, 0.f);
            am2[q] = make_float2(0.f, 0.f);
            app[q] = make_float2(0.f, 0.f);
            axy[q] = make_float2(0.f, 0.f);
        }
        #pragma unroll
        for (int j = 0; j < QR + 10; ++j) {
            const float2 x = p1[(r0 + j) * (IMG_W / 2)];
            const float2 y = p2[(r0 + j) * (IMG_W / 2)];
            const float2 pp = make_float2(fmaf(x.x, x.x, y.x * y.x),
                                          fmaf(x.y, x.y, y.y * y.y));
            const float2 xy = make_float2(x.x * y.x, x.y * y.y);
            #pragma unroll
            for (int q = 0; q < QR; ++q) {
                const int k = j - q;
                if (k >= 0 && k < 11) {
                    const float w = g[k];
                    am1[q] = f2fma(w, x,  am1[q]);
                    am2[q] = f2fma(w, y,  am2[q]);
                    app[q] = f2fma(w, pp, app[q]);
                    axy[q] = f2fma(w, xy, axy[q]);
                }
            }
        }
        // write this iteration's v-stats into buffer p (previous reads of buffer p
        // finished before the barrier of the previous iteration -> safe).
        #pragma unroll
        for (int q = 0; q < QR; ++q) {
            *(float2*)&vrow[p][q][0][woff] = am1[q];
            *(float2*)&vrow[p][q][1][woff] = am2[q];
            *(float2*)&vrow[p][q][2][woff] = app[q];
            *(float2*)&vrow[p][q][3][woff] = axy[q];
        }
        __syncthreads();   // single barrier per iteration (double-buffered handoff)

        // ------------- phase H: horizontal 11-tap conv + SSIM, 4 cols/thread -------------
        const int rr = r0 + hq;
        if (rr < row_end) {
            float aa[4][4];
            #pragma unroll
            for (int ch = 0; ch < 4; ++ch) {
                const float* bc = &vrow[p][hq][ch][0];
                float f[16];
                #pragma unroll
                for (int k = 0; k < 4; ++k) {
                    float4 v = *(const float4*)(bc + roff[k]);
                    f[4*k+0] = v.x; f[4*k+1] = v.y; f[4*k+2] = v.z; f[4*k+3] = v.w;
                }
                #pragma unroll
                for (int j = 0; j < 4; ++j) {
                    float s = 0.f;
                    #pragma unroll
                    for (int k = 0; k < 11; ++k) s = fmaf(g[k], f[j + k], s);
                    aa[ch][j] = s;
                }
            }
            #pragma unroll
            for (int j = 0; j < 4; ++j) {
                if (cb + j < OUT_W) {
                    float mu1 = aa[0][j], mu2 = aa[1][j];
                    float ee  = aa[2][j], e12 = aa[3][j];
                    float mu11 = mu1 * mu1;
                    float mu22 = mu2 * mu2;
                    float mu12 = mu1 * mu2;
                    float mm   = mu11 + mu22;
                    float s12  = e12 - mu12;
                    float spp  = ee - mm;            // s1 + s2
                    float num = fmaf(2.f, mu12, C1) * fmaf(2.f, s12, C2);
                    float den = (mm + C1) * (spp + C2);
                    local = fmaf(num, __builtin_amdgcn_rcpf(den), local);
                }
            }
        }
    }

    // ---------------- reduction: wave shuffle -> LDS -> double atomic ----------------
    #pragma unroll
    for (int off = 32; off > 0; off >>= 1) local += __shfl_down(local, off, 64);
    if ((t & 63) == 0) red[t >> 6] = local;
    __syncthreads();
    if (t == 0) {
        double s = (double)red[0] + (double)red[1] + (double)red[2] + (double)red[3];
        atomicAdd(acc, s);
    }
}

__global__ void ssim_fin(const double* __restrict__ acc, float* __restrict__ out)
{
    out[0] = (float)(acc[0] / TOTAL);
}

extern "C" void kernel_launch(void* const* d_in, const int* in_sizes, int n_in,
                              void* d_out, int out_size, void* d_ws, size_t ws_size,
                              hipStream_t stream)
{
    (void)in_sizes; (void)n_in; (void)out_size; (void)ws_size;
    const float* img1 = (const float*)d_in[0];
    const float* img2 = (const float*)d_in[1];
    double* acc = (double*)d_ws;

    hipMemsetAsync(d_ws, 0, sizeof(double), stream);
    dim3 grid((OUT_H + RPB - 1) / RPB, NIMG);
    hipLaunchKernelGGL(ssim_main, grid, dim3(256), 0, stream, img1, img2, acc);
    hipLaunchKernelGGL(ssim_fin, dim3(1), dim3(1), 0, stream, acc, (float*)d_out);
}

// Round 7
// 246.074 us; speedup vs baseline: 2.7815x; 1.1728x over previous
//
#include <hip/hip_runtime.h>

// SSIM over (32,3,512,512) fp32 pairs, 11x11 gaussian sigma=1.5, VALID conv,
// scalar mean output. Fused separable conv, 4 v-stat channels (x, y, x2+y2,
// x*y) staged in LDS (XOR-swizzled), horizontal 11-tap conv + SSIM + mean.
//
// R4 (2nd resubmit after broker timeouts): persistent rolling row-window.
// QR=4; thread keeps 14 (x,y) float2 rows in registers across iterations,
// loads only 4 new rows/iter (was 12 rows per 2 outputs in R3 = 6x redundancy
// -> ~1.2x). Single-buffer LDS (34.8KB, 4ch x QR=4) + 2 barriers (R0
// structure), phase-H all 256 threads x 8 cols (R0 layout). RPB=48 -> grid
// 1056 = 4.1 blocks/CU. Window shifted BEFORE phase-H to shrink live range;
// launch_bounds(256,2) => ~128 VGPR cap (R1: cap = floor(256/N); N=3's 85
// would spill this structure).

namespace {
constexpr int IMG_H = 512;
constexpr int IMG_W = 512;
constexpr int NIMG  = 96;            // B*C = 32*3
constexpr int OUT_H = 502;
constexpr int OUT_W = 502;
constexpr int RPB   = 48;            // output rows per block
constexpr int QR    = 4;             // output rows per inner iteration
constexpr int WIN   = QR + 10;       // rolling window rows
constexpr int BUFW  = 544;           // 136 col4 slots * 4 floats (512 data + halo/pad)
constexpr double TOTAL = 24192384.0; // 96*502*502

// exp(-k^2/4.5) for k=5..1, normalized at compile time
constexpr double U0 = 0.0038659201;
constexpr double U1 = 0.0285655007;
constexpr double U2 = 0.1353352832366127;
constexpr double U3 = 0.4111122898;
constexpr double U4 = 0.8007374026;
constexpr double S  = 1.0 + 2.0 * (U0 + U1 + U2 + U3 + U4);
}

__device__ __forceinline__ float2 f2fma(float w, float2 a, float2 c) {
    return make_float2(fmaf(w, a.x, c.x), fmaf(w, a.y, c.y));
}

__global__ __launch_bounds__(256, 2) void ssim_main(const float* __restrict__ img1,
                                                    const float* __restrict__ img2,
                                                    double* __restrict__ acc)
{
    __shared__ __align__(16) float vrow[QR][4][BUFW];   // 34816 B
    __shared__ float red[4];

    const float g[11] = {
        (float)(U0/S), (float)(U1/S), (float)(U2/S), (float)(U3/S), (float)(U4/S),
        (float)(1.0/S),
        (float)(U4/S), (float)(U3/S), (float)(U2/S), (float)(U1/S), (float)(U0/S)
    };
    constexpr float C1 = 1e-4f;   // 0.01^2
    constexpr float C2 = 9e-4f;   // 0.03^2

    const int t   = threadIdx.x;
    const int z   = blockIdx.y;
    const int oy0 = blockIdx.x * RPB;
    const int row_end = min(oy0 + RPB, OUT_H);

    const float2* p1 = (const float2*)(img1 + (size_t)z * (IMG_H * IMG_W)) + t;
    const float2* p2 = (const float2*)(img2 + (size_t)z * (IMG_H * IMG_W)) + t;

    // phase-V: thread owns input cols 2t, 2t+1. Swizzled write offset.
    const int c4w  = t >> 1;
    const int woff = ((c4w ^ ((c4w >> 3) & 7)) << 2) + ((t & 1) << 1);

    // phase-H: thread = (row hq 0..3, 8-col group at cb). Swizzled read offsets.
    const int hq = t >> 6;            // 0..3, all 256 threads active
    const int cb = (t & 63) << 3;     // 0..504
    int roff[5];
    #pragma unroll
    for (int k = 0; k < 5; ++k) {
        int c4 = (cb >> 2) + k;       // <= 130 < 136 slots
        roff[k] = (c4 ^ ((c4 >> 3) & 7)) << 2;
    }

    // rolling window: rows r0 .. r0+9 live at loop top
    float2 wx[WIN], wy[WIN];
    #pragma unroll
    for (int j = 0; j < WIN - QR; ++j) {
        wx[j] = p1[(oy0 + j) * (IMG_W / 2)];
        wy[j] = p2[(oy0 + j) * (IMG_W / 2)];
    }

    float local = 0.f;

    for (int r0 = oy0; r0 < row_end; r0 += QR) {
        // ---- load the 4 new window rows (issued early, overlap with conv) ----
        #pragma unroll
        for (int i = 0; i < QR; ++i) {
            const int row = min(r0 + (WIN - QR) + i, IMG_H - 1);  // clamp: tail only
            wx[WIN - QR + i] = p1[row * (IMG_W / 2)];
            wy[WIN - QR + i] = p2[row * (IMG_W / 2)];
        }

        // ---- phase V: vertical 11-tap conv over the window, 4 channels ----
        float2 am1[QR], am2[QR], app[QR], axy[QR];
        #pragma unroll
        for (int q = 0; q < QR; ++q) {
            am1[q] = make_float2(0.f, 0.f);
            am2[q] = make_float2(0.f, 0.f);
            app[q] = make_float2(0.f, 0.f);
            axy[q] = make_float2(0.f, 0.f);
        }
        #pragma unroll
        for (int j = 0; j < WIN; ++j) {
            const float2 x = wx[j], y = wy[j];
            const float2 pp = make_float2(fmaf(x.x, x.x, y.x * y.x),
                                          fmaf(x.y, x.y, y.y * y.y));
            const float2 xy = make_float2(x.x * y.x, x.y * y.y);
            #pragma unroll
            for (int q = 0; q < QR; ++q) {
                const int k = j - q;
                if (k >= 0 && k < 11) {
                    const float w = g[k];
                    am1[q] = f2fma(w, x,  am1[q]);
                    am2[q] = f2fma(w, y,  am2[q]);
                    app[q] = f2fma(w, pp, app[q]);
                    axy[q] = f2fma(w, xy, axy[q]);
                }
            }
        }
        __syncthreads();   // previous iteration's phase-H reads complete
        #pragma unroll
        for (int q = 0; q < QR; ++q) {
            *(float2*)&vrow[q][0][woff] = am1[q];
            *(float2*)&vrow[q][1][woff] = am2[q];
            *(float2*)&vrow[q][2][woff] = app[q];
            *(float2*)&vrow[q][3][woff] = axy[q];
        }
        __syncthreads();   // v-stats visible

        // ---- shift window now: old rows die before phase-H's register peak ----
        #pragma unroll
        for (int j = 0; j < WIN - QR; ++j) { wx[j] = wx[j + QR]; wy[j] = wy[j + QR]; }

        // ---- phase H: horizontal 11-tap conv + SSIM, 8 cols/thread ----
        const int rr = r0 + hq;
        if (rr < row_end) {
            float aa[4][8];
            #pragma unroll
            for (int ch = 0; ch < 4; ++ch) {
                const float* bc = &vrow[hq][ch][0];
                float f[20];
                #pragma unroll
                for (int k = 0; k < 5; ++k) {
                    float4 v = *(const float4*)(bc + roff[k]);
                    f[4*k+0] = v.x; f[4*k+1] = v.y; f[4*k+2] = v.z; f[4*k+3] = v.w;
                }
                #pragma unroll
                for (int j = 0; j < 8; ++j) {
                    float s = 0.f;
                    #pragma unroll
                    for (int k = 0; k < 11; ++k) s = fmaf(g[k], f[j + k], s);
                    aa[ch][j] = s;
                }
            }
            #pragma unroll
            for (int j = 0; j < 8; ++j) {
                if (cb + j < OUT_W) {
                    float mu1 = aa[0][j], mu2 = aa[1][j];
                    float ee  = aa[2][j], e12 = aa[3][j];
                    float mu11 = mu1 * mu1;
                    float mu22 = mu2 * mu2;
                    float mu12 = mu1 * mu2;
                    float mm   = mu11 + mu22;
                    float s12  = e12 - mu12;
                    float spp  = ee - mm;            // s1 + s2
                    float num = fmaf(2.f, mu12, C1) * fmaf(2.f, s12, C2);
                    float den = (mm + C1) * (spp + C2);
                    local = fmaf(num, __builtin_amdgcn_rcpf(den), local);
                }
            }
        }
    }

    // ---------------- reduction: wave shuffle -> LDS -> double atomic ----------------
    #pragma unroll
    for (int off = 32; off > 0; off >>= 1) local += __shfl_down(local, off, 64);
    if ((t & 63) == 0) red[t >> 6] = local;
    __syncthreads();
    if (t == 0) {
        double s = (double)red[0] + (double)red[1] + (double)red[2] + (double)red[3];
        atomicAdd(acc, s);
    }
}

__global__ void ssim_fin(const double* __restrict__ acc, float* __restrict__ out)
{
    out[0] = (float)(acc[0] / TOTAL);
}

extern "C" void kernel_launch(void* const* d_in, const int* in_sizes, int n_in,
                              void* d_out, int out_size, void* d_ws, size_t ws_size,
                              hipStream_t stream)
{
    (void)in_sizes; (void)n_in; (void)out_size; (void)ws_size;
    const float* img1 = (const float*)d_in[0];
    const float* img2 = (const float*)d_in[1];
    double* acc = (double*)d_ws;

    hipMemsetAsync(d_ws, 0, sizeof(double), stream);
    dim3 grid((OUT_H + RPB - 1) / RPB, NIMG);
    hipLaunchKernelGGL(ssim_main, grid, dim3(256), 0, stream, img1, img2, acc);
    hipLaunchKernelGGL(ssim_fin, dim3(1), dim3(1), 0, stream, acc, (float*)d_out);
}

// Round 8
// 243.806 us; speedup vs baseline: 2.8074x; 1.0093x over previous
//
#include <hip/hip_runtime.h>

// SSIM over (32,3,512,512) fp32 pairs, 11x11 gaussian sigma=1.5, VALID conv,
// scalar mean output. Fused separable conv, 4 v-stat channels (x, y, x2+y2,
// x*y) staged in LDS (XOR-swizzled), horizontal 11-tap conv + SSIM + mean.
//
// R5: packed-FP32 phase-V. The vertical pass is natively column-pair SIMD, so
// the window/products/accumulators become ext_vector_type(2) float and all
// conv FMAs go through __builtin_elementwise_fma -> v_pk_fma_f32 (full-rate
// packed on gfx950; R4's VALUBusy=45% matched the SCALAR instr count, i.e.
// SLP never formed pk ops from float2 structs). Phase-V instr count ~halves.
// Everything else (rolling window QR=4, RPB=48, LDS layout, phase-H, launch
// bounds) identical to R4 for clean attribution.

namespace {
constexpr int IMG_H = 512;
constexpr int IMG_W = 512;
constexpr int NIMG  = 96;            // B*C = 32*3
constexpr int OUT_H = 502;
constexpr int OUT_W = 502;
constexpr int RPB   = 48;            // output rows per block
constexpr int QR    = 4;             // output rows per inner iteration
constexpr int WIN   = QR + 10;       // rolling window rows
constexpr int BUFW  = 544;           // 136 col4 slots * 4 floats (512 data + halo/pad)
constexpr double TOTAL = 24192384.0; // 96*502*502

// exp(-k^2/4.5) for k=5..1, normalized at compile time
constexpr double U0 = 0.0038659201;
constexpr double U1 = 0.0285655007;
constexpr double U2 = 0.1353352832366127;
constexpr double U3 = 0.4111122898;
constexpr double U4 = 0.8007374026;
constexpr double S  = 1.0 + 2.0 * (U0 + U1 + U2 + U3 + U4);
}

typedef float vf2 __attribute__((ext_vector_type(2)));

__device__ __forceinline__ vf2 pk_fma(float w, vf2 a, vf2 c) {
    vf2 wv = {w, w};
    return __builtin_elementwise_fma(wv, a, c);   // -> v_pk_fma_f32
}

__global__ __launch_bounds__(256, 2) void ssim_main(const float* __restrict__ img1,
                                                    const float* __restrict__ img2,
                                                    double* __restrict__ acc)
{
    __shared__ __align__(16) float vrow[QR][4][BUFW];   // 34816 B
    __shared__ float red[4];

    const float g[11] = {
        (float)(U0/S), (float)(U1/S), (float)(U2/S), (float)(U3/S), (float)(U4/S),
        (float)(1.0/S),
        (float)(U4/S), (float)(U3/S), (float)(U2/S), (float)(U1/S), (float)(U0/S)
    };
    constexpr float C1 = 1e-4f;   // 0.01^2
    constexpr float C2 = 9e-4f;   // 0.03^2

    const int t   = threadIdx.x;
    const int z   = blockIdx.y;
    const int oy0 = blockIdx.x * RPB;
    const int row_end = min(oy0 + RPB, OUT_H);

    const vf2* p1 = (const vf2*)(img1 + (size_t)z * (IMG_H * IMG_W)) + t;
    const vf2* p2 = (const vf2*)(img2 + (size_t)z * (IMG_H * IMG_W)) + t;

    // phase-V: thread owns input cols 2t, 2t+1. Swizzled write offset.
    const int c4w  = t >> 1;
    const int woff = ((c4w ^ ((c4w >> 3) & 7)) << 2) + ((t & 1) << 1);

    // phase-H: thread = (row hq 0..3, 8-col group at cb). Swizzled read offsets.
    const int hq = t >> 6;            // 0..3, all 256 threads active
    const int cb = (t & 63) << 3;     // 0..504
    int roff[5];
    #pragma unroll
    for (int k = 0; k < 5; ++k) {
        int c4 = (cb >> 2) + k;       // <= 130 < 136 slots
        roff[k] = (c4 ^ ((c4 >> 3) & 7)) << 2;
    }

    // rolling window: rows r0 .. r0+9 live at loop top
    vf2 wx[WIN], wy[WIN];
    #pragma unroll
    for (int j = 0; j < WIN - QR; ++j) {
        wx[j] = p1[(oy0 + j) * (IMG_W / 2)];
        wy[j] = p2[(oy0 + j) * (IMG_W / 2)];
    }

    float local = 0.f;

    for (int r0 = oy0; r0 < row_end; r0 += QR) {
        // ---- load the 4 new window rows (issued early, overlap with conv) ----
        #pragma unroll
        for (int i = 0; i < QR; ++i) {
            const int row = min(r0 + (WIN - QR) + i, IMG_H - 1);  // clamp: tail only
            wx[WIN - QR + i] = p1[row * (IMG_W / 2)];
            wy[WIN - QR + i] = p2[row * (IMG_W / 2)];
        }

        // ---- phase V: vertical 11-tap conv over the window, 4 channels, packed ----
        vf2 am1[QR], am2[QR], app[QR], axy[QR];
        #pragma unroll
        for (int q = 0; q < QR; ++q) {
            am1[q] = (vf2){0.f, 0.f};
            am2[q] = (vf2){0.f, 0.f};
            app[q] = (vf2){0.f, 0.f};
            axy[q] = (vf2){0.f, 0.f};
        }
        #pragma unroll
        for (int j = 0; j < WIN; ++j) {
            const vf2 x = wx[j], y = wy[j];
            const vf2 pp = __builtin_elementwise_fma(y, y, x * x);  // x^2 + y^2
            const vf2 xy = x * y;
            #pragma unroll
            for (int q = 0; q < QR; ++q) {
                const int k = j - q;
                if (k >= 0 && k < 11) {
                    const float w = g[k];
                    am1[q] = pk_fma(w, x,  am1[q]);
                    am2[q] = pk_fma(w, y,  am2[q]);
                    app[q] = pk_fma(w, pp, app[q]);
                    axy[q] = pk_fma(w, xy, axy[q]);
                }
            }
        }
        __syncthreads();   // previous iteration's phase-H reads complete
        #pragma unroll
        for (int q = 0; q < QR; ++q) {
            *(vf2*)&vrow[q][0][woff] = am1[q];
            *(vf2*)&vrow[q][1][woff] = am2[q];
            *(vf2*)&vrow[q][2][woff] = app[q];
            *(vf2*)&vrow[q][3][woff] = axy[q];
        }
        __syncthreads();   // v-stats visible

        // ---- shift window now: old rows die before phase-H's register peak ----
        #pragma unroll
        for (int j = 0; j < WIN - QR; ++j) { wx[j] = wx[j + QR]; wy[j] = wy[j + QR]; }

        // ---- phase H: horizontal 11-tap conv + SSIM, 8 cols/thread ----
        const int rr = r0 + hq;
        if (rr < row_end) {
            float aa[4][8];
            #pragma unroll
            for (int ch = 0; ch < 4; ++ch) {
                const float* bc = &vrow[hq][ch][0];
                float f[20];
                #pragma unroll
                for (int k = 0; k < 5; ++k) {
                    float4 v = *(const float4*)(bc + roff[k]);
                    f[4*k+0] = v.x; f[4*k+1] = v.y; f[4*k+2] = v.z; f[4*k+3] = v.w;
                }
                #pragma unroll
                for (int j = 0; j < 8; ++j) {
                    float s = 0.f;
                    #pragma unroll
                    for (int k = 0; k < 11; ++k) s = fmaf(g[k], f[j + k], s);
                    aa[ch][j] = s;
                }
            }
            #pragma unroll
            for (int j = 0; j < 8; ++j) {
                if (cb + j < OUT_W) {
                    float mu1 = aa[0][j], mu2 = aa[1][j];
                    float ee  = aa[2][j], e12 = aa[3][j];
                    float mu11 = mu1 * mu1;
                    float mu22 = mu2 * mu2;
                    float mu12 = mu1 * mu2;
                    float mm   = mu11 + mu22;
                    float s12  = e12 - mu12;
                    float spp  = ee - mm;            // s1 + s2
                    float num = fmaf(2.f, mu12, C1) * fmaf(2.f, s12, C2);
                    float den = (mm + C1) * (spp + C2);
                    local = fmaf(num, __builtin_amdgcn_rcpf(den), local);
                }
            }
        }
    }

    // ---------------- reduction: wave shuffle -> LDS -> double atomic ----------------
    #pragma unroll
    for (int off = 32; off > 0; off >>= 1) local += __shfl_down(local, off, 64);
    if ((t & 63) == 0) red[t >> 6] = local;
    __syncthreads();
    if (t == 0) {
        double s = (double)red[0] + (double)red[1] + (double)red[2] + (double)red[3];
        atomicAdd(acc, s);
    }
}

__global__ void ssim_fin(const double* __restrict__ acc, float* __restrict__ out)
{
    out[0] = (float)(acc[0] / TOTAL);
}

extern "C" void kernel_launch(void* const* d_in, const int* in_sizes, int n_in,
                              void* d_out, int out_size, void* d_ws, size_t ws_size,
                              hipStream_t stream)
{
    (void)in_sizes; (void)n_in; (void)out_size; (void)ws_size;
    const float* img1 = (const float*)d_in[0];
    const float* img2 = (const float*)d_in[1];
    double* acc = (double*)d_ws;

    hipMemsetAsync(d_ws, 0, sizeof(double), stream);
    dim3 grid((OUT_H + RPB - 1) / RPB, NIMG);
    hipLaunchKernelGGL(ssim_main, grid, dim3(256), 0, stream, img1, img2, acc);
    hipLaunchKernelGGL(ssim_fin, dim3(1), dim3(1), 0, stream, acc, (float*)d_out);
}